// Round 1
// baseline (641.600 us; speedup 1.0000x reference)
//
#include <hip/hip_runtime.h>
#include <math.h>

#define BATCH 32
#define CHAN  512
#define HW    4096
#define KSEL  256

// ---------------------------------------------------------------------------
// Kernel 1: per-(b,c) cosine similarity over the 4096 spatial elements.
// One block per (b,c); 256 threads; each thread does 4 float4 loads of x and y.
// Tree reduction: per-thread partial -> wave shfl -> LDS across 4 waves.
// ---------------------------------------------------------------------------
__global__ __launch_bounds__(256) void sim_kernel(const float* __restrict__ x,
                                                  const float* __restrict__ y,
                                                  float* __restrict__ sims) {
    const int bc = blockIdx.x;
    const float4* xp = (const float4*)(x + (size_t)bc * HW);
    const float4* yp = (const float4*)(y + (size_t)bc * HW);
    const int t = threadIdx.x;

    float dot = 0.f, xx = 0.f, yy = 0.f;
    #pragma unroll
    for (int i = t; i < HW / 4; i += 256) {
        float4 a = xp[i];
        float4 b = yp[i];
        dot += a.x * b.x + a.y * b.y + a.z * b.z + a.w * b.w;
        xx  += a.x * a.x + a.y * a.y + a.z * a.z + a.w * a.w;
        yy  += b.x * b.x + b.y * b.y + b.z * b.z + b.w * b.w;
    }

    // wave (64-lane) reduction
    #pragma unroll
    for (int off = 32; off > 0; off >>= 1) {
        dot += __shfl_down(dot, off);
        xx  += __shfl_down(xx,  off);
        yy  += __shfl_down(yy,  off);
    }

    __shared__ float sdot[4], sxx[4], syy[4];
    const int wave = t >> 6, lane = t & 63;
    if (lane == 0) { sdot[wave] = dot; sxx[wave] = xx; syy[wave] = yy; }
    __syncthreads();
    if (t == 0) {
        float d  = (sdot[0] + sdot[1]) + (sdot[2] + sdot[3]);
        float x2 = (sxx[0]  + sxx[1])  + (sxx[2]  + sxx[3]);
        float y2 = (syy[0]  + syy[1])  + (syy[2]  + syy[3]);
        float nx = sqrtf(x2);
        float ny = sqrtf(y2);
        sims[bc] = d / (fmaxf(nx, 1e-8f) * fmaxf(ny, 1e-8f));
    }
}

// ---------------------------------------------------------------------------
// Kernel 2: per-batch exact K-smallest selection + softmax -> sparse gate.
// One block per batch, 512 threads (one per channel). Rank by O(C^2) count in
// LDS with jax.lax.top_k tie-break semantics (among equal values, lower index
// selected first). Selected channels get softmax weight; others 0.
// ---------------------------------------------------------------------------
__global__ __launch_bounds__(512) void gate_kernel(const float* __restrict__ sims,
                                                   float* __restrict__ gate) {
    const int b = blockIdx.x;
    const int c = threadIdx.x;

    __shared__ float sv[CHAN];
    const float v = sims[b * CHAN + c];
    sv[c] = v;
    __syncthreads();

    // rank among the batch's 512 sims (smallest-first, index tie-break)
    int rank = 0;
    for (int j = 0; j < CHAN; ++j) {
        float w = sv[j];
        rank += (w < v) || (w == v && j < c);
    }
    const bool sel = rank < KSEL;

    __shared__ float red[CHAN];
    // max over selected values
    red[c] = sel ? v : -INFINITY;
    __syncthreads();
    #pragma unroll
    for (int s = CHAN / 2; s > 0; s >>= 1) {
        if (c < s) red[c] = fmaxf(red[c], red[c + s]);
        __syncthreads();
    }
    const float m = red[0];
    __syncthreads();

    // sum of exp over selected
    const float e = sel ? expf(v - m) : 0.f;
    red[c] = e;
    __syncthreads();
    #pragma unroll
    for (int s = CHAN / 2; s > 0; s >>= 1) {
        if (c < s) red[c] += red[c + s];
        __syncthreads();
    }
    const float sum = red[0];

    gate[b * CHAN + c] = sel ? (e / sum) : 0.f;
}

// ---------------------------------------------------------------------------
// Kernel 3: out[b,c,:] = gate[b,c] * x[b,c,:]. One block per (b,c), float4.
// ---------------------------------------------------------------------------
__global__ __launch_bounds__(256) void scale_kernel(const float* __restrict__ x,
                                                    const float* __restrict__ gate,
                                                    float* __restrict__ out) {
    const int bc = blockIdx.x;
    const float g = gate[bc];
    const float4* xp = (const float4*)(x + (size_t)bc * HW);
    float4* op = (float4*)(out + (size_t)bc * HW);
    const int t = threadIdx.x;
    #pragma unroll
    for (int i = t; i < HW / 4; i += 256) {
        float4 a = xp[i];
        a.x *= g; a.y *= g; a.z *= g; a.w *= g;
        op[i] = a;
    }
}

extern "C" void kernel_launch(void* const* d_in, const int* in_sizes, int n_in,
                              void* d_out, int out_size, void* d_ws, size_t ws_size,
                              hipStream_t stream) {
    const float* x = (const float*)d_in[0];
    const float* y = (const float*)d_in[1];
    float* out = (float*)d_out;

    float* sims = (float*)d_ws;              // BATCH*CHAN floats
    float* gate = sims + BATCH * CHAN;       // BATCH*CHAN floats

    sim_kernel<<<BATCH * CHAN, 256, 0, stream>>>(x, y, sims);
    gate_kernel<<<BATCH, CHAN, 0, stream>>>(sims, gate);
    scale_kernel<<<BATCH * CHAN, 256, 0, stream>>>(x, gate, out);
}

// Round 2
// 600.125 us; speedup vs baseline: 1.0691x; 1.0691x over previous
//
#include <hip/hip_runtime.h>
#include <math.h>

#define BATCH 32
#define CHAN  512
#define HW    4096
#define KSEL  256

typedef float float4v __attribute__((ext_vector_type(4)));

// ---------------------------------------------------------------------------
// Kernel 1: per-(b,c) cosine similarity over the 4096 spatial elements.
// x loaded normally (we WANT it to stay in L3 for the scale pass);
// y loaded nontemporal (streamed once, never reused -> don't pollute L3).
// ---------------------------------------------------------------------------
__global__ __launch_bounds__(256) void sim_kernel(const float* __restrict__ x,
                                                  const float* __restrict__ y,
                                                  float* __restrict__ sims) {
    const int bc = blockIdx.x;
    const float4v* xp = (const float4v*)(x + (size_t)bc * HW);
    const float4v* yp = (const float4v*)(y + (size_t)bc * HW);
    const int t = threadIdx.x;

    float dot = 0.f, xx = 0.f, yy = 0.f;
    #pragma unroll
    for (int i = t; i < HW / 4; i += 256) {
        float4v a = xp[i];
        float4v b = __builtin_nontemporal_load(yp + i);
        dot += a.x * b.x + a.y * b.y + a.z * b.z + a.w * b.w;
        xx  += a.x * a.x + a.y * a.y + a.z * a.z + a.w * a.w;
        yy  += b.x * b.x + b.y * b.y + b.z * b.z + b.w * b.w;
    }

    // wave (64-lane) reduction
    #pragma unroll
    for (int off = 32; off > 0; off >>= 1) {
        dot += __shfl_down(dot, off);
        xx  += __shfl_down(xx,  off);
        yy  += __shfl_down(yy,  off);
    }

    __shared__ float sdot[4], sxx[4], syy[4];
    const int wave = t >> 6, lane = t & 63;
    if (lane == 0) { sdot[wave] = dot; sxx[wave] = xx; syy[wave] = yy; }
    __syncthreads();
    if (t == 0) {
        float d  = (sdot[0] + sdot[1]) + (sdot[2] + sdot[3]);
        float x2 = (sxx[0]  + sxx[1])  + (sxx[2]  + sxx[3]);
        float y2 = (syy[0]  + syy[1])  + (syy[2]  + syy[3]);
        float nx = sqrtf(x2);
        float ny = sqrtf(y2);
        sims[bc] = d / (fmaxf(nx, 1e-8f) * fmaxf(ny, 1e-8f));
    }
}

// ---------------------------------------------------------------------------
// Kernel 2: per-batch exact K-smallest selection + softmax -> sparse gate.
// One block per batch, 512 threads (one per channel). Rank by O(C^2) count in
// LDS with jax.lax.top_k tie-break semantics (among equal values, lower index
// selected first). Selected channels get softmax weight; others 0.
// ---------------------------------------------------------------------------
__global__ __launch_bounds__(512) void gate_kernel(const float* __restrict__ sims,
                                                   float* __restrict__ gate) {
    const int b = blockIdx.x;
    const int c = threadIdx.x;

    __shared__ float sv[CHAN];
    const float v = sims[b * CHAN + c];
    sv[c] = v;
    __syncthreads();

    // rank among the batch's 512 sims (smallest-first, index tie-break)
    int rank = 0;
    for (int j = 0; j < CHAN; ++j) {
        float w = sv[j];
        rank += (w < v) || (w == v && j < c);
    }
    const bool sel = rank < KSEL;

    __shared__ float red[CHAN];
    // max over selected values
    red[c] = sel ? v : -INFINITY;
    __syncthreads();
    #pragma unroll
    for (int s = CHAN / 2; s > 0; s >>= 1) {
        if (c < s) red[c] = fmaxf(red[c], red[c + s]);
        __syncthreads();
    }
    const float m = red[0];
    __syncthreads();

    // sum of exp over selected
    const float e = sel ? expf(v - m) : 0.f;
    red[c] = e;
    __syncthreads();
    #pragma unroll
    for (int s = CHAN / 2; s > 0; s >>= 1) {
        if (c < s) red[c] += red[c + s];
        __syncthreads();
    }
    const float sum = red[0];

    gate[b * CHAN + c] = sel ? (e / sum) : 0.f;
}

// ---------------------------------------------------------------------------
// Kernel 3: out[b,c,:] = gate[b,c] * x[b,c,:]. One block per (b,c).
// Zero-gate channels (half of them!) skip the x read entirely and just store
// zeros. Stores are nontemporal so the write stream doesn't evict x from L3.
// ---------------------------------------------------------------------------
__global__ __launch_bounds__(256) void scale_kernel(const float* __restrict__ x,
                                                    const float* __restrict__ gate,
                                                    float* __restrict__ out) {
    const int bc = blockIdx.x;
    const float g = gate[bc];                 // wave-uniform per block
    const float4v* xp = (const float4v*)(x + (size_t)bc * HW);
    float4v* op = (float4v*)(out + (size_t)bc * HW);
    const int t = threadIdx.x;

    if (g != 0.f) {
        #pragma unroll
        for (int i = t; i < HW / 4; i += 256) {
            float4v a = xp[i];
            a.x *= g; a.y *= g; a.z *= g; a.w *= g;
            __builtin_nontemporal_store(a, op + i);
        }
    } else {
        float4v z = {0.f, 0.f, 0.f, 0.f};
        #pragma unroll
        for (int i = t; i < HW / 4; i += 256) {
            __builtin_nontemporal_store(z, op + i);
        }
    }
}

extern "C" void kernel_launch(void* const* d_in, const int* in_sizes, int n_in,
                              void* d_out, int out_size, void* d_ws, size_t ws_size,
                              hipStream_t stream) {
    const float* x = (const float*)d_in[0];
    const float* y = (const float*)d_in[1];
    float* out = (float*)d_out;

    float* sims = (float*)d_ws;              // BATCH*CHAN floats
    float* gate = sims + BATCH * CHAN;       // BATCH*CHAN floats

    sim_kernel<<<BATCH * CHAN, 256, 0, stream>>>(x, y, sims);
    gate_kernel<<<BATCH, CHAN, 0, stream>>>(sims, gate);
    scale_kernel<<<BATCH * CHAN, 256, 0, stream>>>(x, gate, out);
}